// Round 7
// baseline (185.978 us; speedup 1.0000x reference)
//
#include <hip/hip_runtime.h>

namespace {

constexpr int L = 3264;
constexpr int K = 12;
constexpr int S = 8;
constexpr int B = 64;
constexpr int A = 4;
constexpr int R = 816;            // L / LOCC
constexpr int NOFF = 21;          // delays -10..10
constexpr int PEAK_STEP = L / K;  // 272
constexpr float TWO_PI = 6.28318530717958647692f;
constexpr float CINV = TWO_PI / (float)L;
constexpr int NCHUNK = (L + 255) / 256;  // 13
constexpr int HS_MAX = 66;        // max havg slice entries per chunk

__device__ __forceinline__ float rfl(float x) {
    return __uint_as_float(__builtin_amdgcn_readfirstlane(__float_as_uint(x)));
}

__device__ __forceinline__ float2 cmul(float2 a, float2 b) {
    return make_float2(a.x * b.x - a.y * b.y, a.x * b.y + a.y * b.x);
}

// ---------------------------------------------------------------------------
// Kernel 0: phasor stream tables.
//   phT[t][l] = e^{+i*2pi*((t-10)*l mod L)/L}   t in [0,21)   (548 KB)
//   phI[s][l] = e^{+i*2pi*(ideal_s*l mod L)/L}  s in [0,8)    (209 KB)
// ph_m(s,b,l) = phI[s][l] * phT[toff+10][l]; ph_T(s,b,l) = phT[toff+10][l].
// ---------------------------------------------------------------------------
__global__ __launch_bounds__(256)
void k_tables(const int* __restrict__ cs,
              float2* __restrict__ phT, float2* __restrict__ phI)
{
    const int g = blockIdx.x * 256 + threadIdx.x;
    if (g < NOFF * L) {
        const int t = g / L, l = g - t * L;
        int j = ((t - 10) * l) % L; if (j < 0) j += L;   // |.| <= 32640
        float sv, cv; __sincosf(CINV * (float)j, &sv, &cv);
        phT[g] = make_float2(cv, sv);
    } else if (g < (NOFF + S) * L) {
        const int q = g - NOFF * L;
        const int s = q / L, l = q - s * L;
        const int ideal = ((K - cs[s]) % K) * PEAK_STEP;
        const int j = (ideal * l) % L;                   // <= 9.8M, int32 ok
        float sv, cv; __sincosf(CINV * (float)j, &sv, &cv);
        phI[q] = make_float2(cv, sv);
    }
}

// ---------------------------------------------------------------------------
// DFT partial over the full row (LDS-staged) at NB consecutive bins starting
// at idx0d0, k-partition: k = grouplane + 256*it (12 iters + tail<192).
// Register phasors rotated by block-uniform per-bin SGPR steps.
// ---------------------------------------------------------------------------
template <int NB>
__device__ __forceinline__ void dft_bins(
    const float* __restrict__ lscr, const float* __restrict__ lsci,
    int idx0d0, int grouplane, int lane, int w, float2 (*red)[11])
{
    // initial phasors w_d = e^{i*2pi*grouplane*(idx0d0+d)/L}
    const int jb = (grouplane * idx0d0) % L;            // <= 832K
    float br, bi; __sincosf(CINV * (float)jb, &bi, &br);
    float lr, li; __sincosf(CINV * (float)grouplane, &li, &lr);
    float pwr[NB], pwi[NB], ar[NB], ai[NB];
    pwr[0] = br; pwi[0] = bi;
    #pragma unroll
    for (int d = 1; d < NB; ++d) {
        pwr[d] = pwr[d-1] * lr - pwi[d-1] * li;
        pwi[d] = pwr[d-1] * li + pwi[d-1] * lr;
    }
    #pragma unroll
    for (int d = 0; d < NB; ++d) { ar[d] = 0.f; ai[d] = 0.f; }

    // per-bin k-stride-256 steps e^{i*2pi*256*(idx0d0+d)/L} — uniform -> SGPR
    const int js = (256 * idx0d0) % L;
    float s0r, s0i; __sincosf(CINV * (float)js, &s0i, &s0r);
    float c8r, c8i; __sincosf(CINV * 256.0f, &c8i, &c8r);
    float str_[NB], sti_[NB];
    {
        float cr = s0r, ci = s0i;
        #pragma unroll
        for (int d = 0; d < NB; ++d) {
            str_[d] = rfl(cr); sti_[d] = rfl(ci);
            const float nr2 = cr * c8r - ci * c8i;
            ci = cr * c8i + ci * c8r;
            cr = nr2;
        }
    }

    for (int it = 0; it < 12; ++it) {
        const int k = grouplane + (it << 8);
        const float xr = lscr[k];
        const float xi = lsci[k];
        #pragma unroll
        for (int d = 0; d < NB; ++d) {
            ar[d] += xr * pwr[d] - xi * pwi[d];
            ai[d] += xr * pwi[d] + xi * pwr[d];
            const float nr2 = pwr[d] * str_[d] - pwi[d] * sti_[d];
            pwi[d] = pwr[d] * sti_[d] + pwi[d] * str_[d];
            pwr[d] = nr2;
        }
    }
    if (grouplane < 192) {                              // tail k = gl + 3072
        const float xr = lscr[grouplane + 3072];
        const float xi = lsci[grouplane + 3072];
        #pragma unroll
        for (int d = 0; d < NB; ++d) {
            ar[d] += xr * pwr[d] - xi * pwi[d];
            ai[d] += xr * pwi[d] + xi * pwr[d];
        }
    }

    #pragma unroll
    for (int d = 0; d < NB; ++d) {
        float r = ar[d], im = ai[d];
        #pragma unroll
        for (int o = 32; o > 0; o >>= 1) {
            r  += __shfl_xor(r, o);
            im += __shfl_xor(im, o);
        }
        if (lane == 0) red[w][d] = make_float2(r, im);
    }
}

// ---------------------------------------------------------------------------
// Kernel 1a: one block per LS row (s,b,a) -> 2048 blocks, 512 threads.
// Row staged ONCE into LDS; wave-group 0 (waves 0-3) computes bins 0-9,
// group 1 (waves 4-7) bins 10-20. Same k-partition/reduce order as before.
// ---------------------------------------------------------------------------
__global__ __launch_bounds__(512)
void k_dft(const float* __restrict__ lsr, const float* __restrict__ lsi,
           const int* __restrict__ cs, float* __restrict__ pow_out)
{
    __shared__ float lscr[L];              // 13056 B
    __shared__ float lsci[L];              // 13056 B
    __shared__ float2 red[8][11];          // 704 B

    const int row = blockIdx.x;            // sb*A + a
    const int sb = row >> 2;
    const int a = row & 3;
    const int s = sb >> 6;
    const int tid = threadIdx.x;
    const int lane = tid & 63;
    const int w = tid >> 6;                // wave 0..7
    const int grouplane = tid & 255;
    const int grp = tid >> 8;              // 0: bins 0-9, 1: bins 10-20

    // stage row (float4 global loads, read exactly once)
    {
        const float4* __restrict__ pr4 = (const float4*)(lsr + (size_t)row * L);
        const float4* __restrict__ pi4 = (const float4*)(lsi + (size_t)row * L);
        for (int idx = tid; idx < L / 4; idx += 512) {
            const float4 r4 = pr4[idx];
            const float4 i4 = pi4[idx];
            ((float4*)lscr)[idx] = r4;
            ((float4*)lsci)[idx] = i4;
        }
    }
    __syncthreads();

    const int ideal = ((K - cs[s]) % K) * PEAK_STEP;
    int idx0 = (ideal - 10) % L; if (idx0 < 0) idx0 += L;
    const int d0 = grp ? 10 : 0;
    const int idx0d0 = (idx0 + d0) % L;

    if (grp) dft_bins<11>(lscr, lsci, idx0d0, grouplane, lane, w, red);
    else     dft_bins<10>(lscr, lsci, idx0d0, grouplane, lane, w, red);
    __syncthreads();

    if (tid < NOFF) {
        const int d = tid;
        const int g = (d < 10) ? 0 : 1;
        const int dl = d - g * 10;
        float rr = 0.f, ii = 0.f;
        #pragma unroll
        for (int q = 0; q < 4; ++q) {
            rr += red[4 * g + q][dl].x;
            ii += red[4 * g + q][dl].y;
        }
        pow_out[sb * (NOFF * A) + d * A + a] = rr * rr + ii * ii;
    }
}

// ---------------------------------------------------------------------------
// Kernel 1b: per sb: sum antenna powers, first-max argmax (jnp semantics).
// ---------------------------------------------------------------------------
__global__ __launch_bounds__(64)
void k_argmax(const float* __restrict__ pow_in, const int* __restrict__ cs,
              int* __restrict__ toff_out)
{
    const int sb = blockIdx.x;
    const int lane = threadIdx.x;

    float pw = -1.f;
    if (lane < NOFF) {
        const float4 p4 = *(const float4*)(pow_in + sb * (NOFF * A) + lane * A);
        pw = p4.x + p4.y + p4.z + p4.w;
    }
    float mx = pw;
    #pragma unroll
    for (int o = 32; o > 0; o >>= 1) mx = fmaxf(mx, __shfl_xor(mx, o));
    const unsigned long long msk = __ballot(pw == mx);
    const int argd = __ffsll(msk) - 1;     // lowest lane = first max
    if (lane == 0) toff_out[sb] = argd - 10;
}

// ---------------------------------------------------------------------------
// Kernel 2: per (b,a,chunk). h_avg slice recomputed into LDS, then interp +
// residual + timing recovery. All phasors from the coalesced phI/phT streams
// (one cmul each) — zero divergent gathers, zero trig.
// ---------------------------------------------------------------------------
__global__ __launch_bounds__(256)
void k_final(const float* __restrict__ lsr, const float* __restrict__ lsi,
             const int* __restrict__ toff_arr,
             const float2* __restrict__ phT, const float2* __restrict__ phI,
             float* __restrict__ out)
{
    __shared__ float2 hs[S][HS_MAX];       // 4224 B
    __shared__ float2 emp_s[S];
    __shared__ int tfs[S];

    const int bid = blockIdx.x;
    const int chunk = bid % NCHUNK;
    const int ba = bid / NCHUNK;
    const int b = ba >> 2;
    const int a = ba & 3;
    const int tid = threadIdx.x;

    if (tid < S) {
        const int tf = toff_arr[tid * B + b] + 10;     // row in phT
        tfs[tid] = tf;
        emp_s[tid] = cmul(phI[tid * L + 1], phT[tf * L + 1]);  // e^{i*2pi*m/L}
    }
    __syncthreads();

    const int imin = max(0, chunk * 64 - 1);
    const int imax = min(R - 1, chunk * 64 + 64);
    const int cnt = imax - imin + 1;       // <= 66

    for (int t = tid; t < S * HS_MAX; t += 256) {
        const int s = t / HS_MAX;
        const int ii = t - s * HS_MAX;
        if (ii < cnt) {
            const int i = imin + ii;
            const int sb = s * B + b;
            const float2 emp = emp_s[s];
            float2 w2 = cmul(phI[s * L + 4 * i], phT[tfs[s] * L + 4 * i]);
            const float4 xr = *(const float4*)(lsr + ((size_t)sb * A + a) * L + 4 * i);
            const float4 xi = *(const float4*)(lsi + ((size_t)sb * A + a) * L + 4 * i);
            float wr = w2.x, wi = w2.y;
            float are, aim, nr;
            are  = xr.x * wr - xi.x * wi;  aim  = xr.x * wi + xi.x * wr;
            nr = wr * emp.x - wi * emp.y;  wi = wr * emp.y + wi * emp.x;  wr = nr;
            are += xr.y * wr - xi.y * wi;  aim += xr.y * wi + xi.y * wr;
            nr = wr * emp.x - wi * emp.y;  wi = wr * emp.y + wi * emp.x;  wr = nr;
            are += xr.z * wr - xi.z * wi;  aim += xr.z * wi + xi.z * wr;
            nr = wr * emp.x - wi * emp.y;  wi = wr * emp.y + wi * emp.x;  wr = nr;
            are += xr.w * wr - xi.w * wi;  aim += xr.w * wi + xi.w * wr;
            hs[s][ii] = make_float2(are * 0.25f, aim * 0.25f);
        }
    }
    __syncthreads();

    const int l = chunk * 256 + tid;
    if (l >= L) return;

    float t2 = ((float)l - 1.5f) * 0.25f;
    t2 = fminf(fmaxf(t2, 0.0f), (float)(R - 1));
    const int i0 = (int)t2;
    const int i1 = min(i0 + 1, R - 1);
    const float frac = t2 - (float)i0;

    float hire[S], hiim[S], pmre[S], pmim[S], ptre[S], ptim[S];
    float rre = 0.f, rim = 0.f;

    #pragma unroll
    for (int s = 0; s < S; ++s) {
        const float2 pt = phT[tfs[s] * L + l];
        const float2 wm = cmul(phI[s * L + l], pt);
        const float2 h0 = hs[s][i0 - imin];
        const float2 h1 = hs[s][i1 - imin];
        const float hr = h0.x * (1.f - frac) + h1.x * frac;
        const float hi = h0.y * (1.f - frac) + h1.y * frac;
        hire[s] = hr; hiim[s] = hi;
        pmre[s] = wm.x; pmim[s] = wm.y;
        ptre[s] = pt.x; ptim[s] = pt.y;
        rre += hr * wm.x + hi * wm.y;                  // h * conj(ph_m)
        rim += hi * wm.x - hr * wm.y;
    }

    const size_t off0 = ((size_t)(b * A + a)) * L + l;
    const float resre = lsr[off0] - rre;
    const float resim = lsi[off0] - rim;

    #pragma unroll
    for (int s = 0; s < S; ++s) {
        const float wre = hire[s] + resre * pmre[s] - resim * pmim[s];
        const float wim = hiim[s] + resre * pmim[s] + resim * pmre[s];
        const float fre = wre * ptre[s] + wim * ptim[s];   // * conj(ph_T)
        const float fim = wim * ptre[s] - wre * ptim[s];
        const size_t o = (((size_t)(s * B + b)) * A + a) * L + l;
        __builtin_nontemporal_store(fre, &out[o]);
        __builtin_nontemporal_store(fim, &out[(size_t)S * B * A * L + o]);
    }
}

}  // namespace

extern "C" void kernel_launch(void* const* d_in, const int* in_sizes, int n_in,
                              void* d_out, int out_size, void* d_ws, size_t ws_size,
                              hipStream_t stream) {
    (void)in_sizes; (void)n_in; (void)out_size; (void)ws_size;
    const float* lsr = (const float*)d_in[0];
    const float* lsi = (const float*)d_in[1];
    const int*   cs  = (const int*)d_in[2];
    // d_in[3] (noise_powers) unused: mmse_module is identity.

    int* toff = (int*)d_ws;                                  // 512 ints @ 0
    float2* phT  = (float2*)((char*)d_ws + 4096);            // 21*L*8 = 548352 B
    float2* phI  = (float2*)((char*)d_ws + 4096 + 548352);   // 8*L*8 = 208896 B
    float*  powb = (float*)((char*)d_ws + 786432);           // 512*84*4 B

    const int ntab = ((NOFF + S) * L + 255) / 256;
    k_tables<<<ntab, 256, 0, stream>>>(cs, phT, phI);
    k_dft   <<<S * B * A, 512, 0, stream>>>(lsr, lsi, cs, powb);
    k_argmax<<<S * B, 64, 0, stream>>>(powb, cs, toff);
    k_final <<<B * A * NCHUNK, 256, 0, stream>>>(lsr, lsi, toff, phT, phI,
                                                 (float*)d_out);
}

// Round 8
// 181.054 us; speedup vs baseline: 1.0272x; 1.0272x over previous
//
#include <hip/hip_runtime.h>

namespace {

constexpr int L = 3264;
constexpr int K = 12;
constexpr int S = 8;
constexpr int B = 64;
constexpr int A = 4;
constexpr int R = 816;            // L / LOCC
constexpr int NOFF = 21;          // delays -10..10
constexpr int PEAK_STEP = L / K;  // 272
constexpr float TWO_PI = 6.28318530717958647692f;
constexpr float CINV = TWO_PI / (float)L;
constexpr int NCHUNK = (L + 255) / 256;  // 13

__device__ __forceinline__ float2 cmul(float2 a, float2 b) {
    return make_float2(a.x * b.x - a.y * b.y, a.x * b.y + a.y * b.x);
}

__device__ __forceinline__ float rdl(float v, int d) {
    return __uint_as_float(__builtin_amdgcn_readlane(__float_as_uint(v), d));
}

// ---------------------------------------------------------------------------
// Kernel 0: phasor stream tables (all coalesced consumers).
//   phT[t][l] = e^{+i*2pi*((t-10)*l mod L)/L}   t in [0,21)   (548 KB)
//   phI[s][l] = e^{+i*2pi*(ideal_s*l mod L)/L}  s in [0,8)    (209 KB)
//   tw[j]     = e^{+i*2pi*j/L}                  j in [0,L)    (26 KB)
// ---------------------------------------------------------------------------
__global__ __launch_bounds__(256)
void k_tables(const int* __restrict__ cs, float2* __restrict__ phT,
              float2* __restrict__ phI, float2* __restrict__ tw)
{
    const int g = blockIdx.x * 256 + threadIdx.x;
    if (g < NOFF * L) {
        const int t = g / L, l = g - t * L;
        int j = ((t - 10) * l) % L; if (j < 0) j += L;   // |.| <= 32630
        float sv, cv; __sincosf(CINV * (float)j, &sv, &cv);
        phT[g] = make_float2(cv, sv);
    } else if (g < (NOFF + S) * L) {
        const int q = g - NOFF * L;
        const int s = q / L, l = q - s * L;
        const int ideal = ((K - cs[s]) % K) * PEAK_STEP;
        const int j = (ideal * l) % L;                   // <= 9.8M, int32 ok
        float sv, cv; __sincosf(CINV * (float)j, &sv, &cv);
        phI[q] = make_float2(cv, sv);
    } else if (g < (NOFF + S + 1) * L) {
        const int j = g - (NOFF + S) * L;
        float sv, cv; __sincosf(CINV * (float)j, &sv, &cv);
        tw[j] = make_float2(cv, sv);
    }
}

// ---------------------------------------------------------------------------
// Kernel 1a: one block per LS row (s,b,a) -> 2048 blocks, 512 threads.
// Group 0 (waves 0-3): bins 0-9(+dup10); group 1 (waves 4-7): bins 10-20.
// Zero sincos: initial phasors / bin-chain factor / per-bin SGPR steps all
// from stream tables. 11 independent register phasors -> ILP in the 8-FMA
// per-bin inner body. Row read once (group 1 re-reads through L1).
// ---------------------------------------------------------------------------
__global__ __launch_bounds__(512)
void k_dft(const float* __restrict__ lsr, const float* __restrict__ lsi,
           const int* __restrict__ cs,
           const float2* __restrict__ phT, const float2* __restrict__ phI,
           const float2* __restrict__ tw, float* __restrict__ pow_out)
{
    __shared__ float2 red[8][11];

    const int row = blockIdx.x;            // sb*A + a
    const int sb = row >> 2;
    const int a = row & 3;
    const int s = sb >> 6;
    const int tid = threadIdx.x;
    const int lane = tid & 63;
    const int w = tid >> 6;                // wave 0..7
    const int gl = tid & 255;              // lane-in-group (= starting k)
    const int grp = tid >> 8;              // 0: bins 0-9, 1: bins 10-20
    const int d0 = grp ? 10 : 0;

    const int ideal = ((K - cs[s]) % K) * PEAK_STEP;
    int idx0 = ideal - 10; if (idx0 < 0) idx0 += L;    // bin0 index, nonneg

    // initial phasor w0 = e^{i*2pi*gl*(idx0+d0)/L} = phI[s][gl]*phT[d0][gl]
    const float2 w0 = cmul(phI[s * L + gl], phT[d0 * L + gl]);
    const float2 lv = tw[gl];              // bin->bin+1 factor e^{i*2pi*gl/L}

    // per-bin k-stride-256 steps e^{i*2pi*256*bin_d/L} — uniform -> SGPR
    {
    }
    int bidx = idx0 + d0 + (lane < 11 ? lane : 10);
    if (bidx >= L) bidx -= L;
    const int js = (256 * bidx) % L;       // <= 835K, int32 ok
    const float2 sv = tw[js];
    float str_[11], sti_[11];
    #pragma unroll
    for (int d = 0; d < 11; ++d) {
        str_[d] = rdl(sv.x, d);
        sti_[d] = rdl(sv.y, d);
    }

    float pwr[11], pwi[11], ar[11], ai[11];
    {
        float cr = w0.x, ci = w0.y;
        pwr[0] = cr; pwi[0] = ci;
        #pragma unroll
        for (int d = 1; d < 11; ++d) {
            const float nr = cr * lv.x - ci * lv.y;
            ci = cr * lv.y + ci * lv.x;
            cr = nr;
            pwr[d] = cr; pwi[d] = ci;
        }
    }
    #pragma unroll
    for (int d = 0; d < 11; ++d) { ar[d] = 0.f; ai[d] = 0.f; }

    const float* __restrict__ pr  = lsr + (size_t)row * L;
    const float* __restrict__ pi_ = lsi + (size_t)row * L;

    for (int it = 0; it < 12; ++it) {      // k = gl + 256*it
        const float xr = pr[gl + (it << 8)];
        const float xi = pi_[gl + (it << 8)];
        #pragma unroll
        for (int d = 0; d < 11; ++d) {
            ar[d] += xr * pwr[d] - xi * pwi[d];
            ai[d] += xr * pwi[d] + xi * pwr[d];
            const float nr = pwr[d] * str_[d] - pwi[d] * sti_[d];
            pwi[d] = pwr[d] * sti_[d] + pwi[d] * str_[d];
            pwr[d] = nr;
        }
    }
    if (gl < 192) {                        // tail k = gl + 3072 < 3264
        const float xr = pr[gl + 3072];
        const float xi = pi_[gl + 3072];
        #pragma unroll
        for (int d = 0; d < 11; ++d) {
            ar[d] += xr * pwr[d] - xi * pwi[d];
            ai[d] += xr * pwi[d] + xi * pwr[d];
        }
    }

    #pragma unroll
    for (int d = 0; d < 11; ++d) {
        float r = ar[d], im = ai[d];
        #pragma unroll
        for (int o = 32; o > 0; o >>= 1) {
            r  += __shfl_xor(r, o);
            im += __shfl_xor(im, o);
        }
        if (lane == 0) red[w][d] = make_float2(r, im);
    }
    __syncthreads();

    if (tid < NOFF) {
        const int d = tid;
        const int g = (d < 10) ? 0 : 1;
        const int dl = d - g * 10;
        float rr = 0.f, ii = 0.f;
        #pragma unroll
        for (int q = 0; q < 4; ++q) {
            rr += red[4 * g + q][dl].x;
            ii += red[4 * g + q][dl].y;
        }
        pow_out[sb * (NOFF * A) + d * A + a] = rr * rr + ii * ii;
    }
}

// ---------------------------------------------------------------------------
// Kernel 1b: per sb: sum antenna powers, first-max argmax (jnp semantics).
// ---------------------------------------------------------------------------
__global__ __launch_bounds__(64)
void k_argmax(const float* __restrict__ pow_in, int* __restrict__ toff_out)
{
    const int sb = blockIdx.x;
    const int lane = threadIdx.x;

    float pw = -1.f;
    if (lane < NOFF) {
        const float4 p4 = *(const float4*)(pow_in + sb * (NOFF * A) + lane * A);
        pw = p4.x + p4.y + p4.z + p4.w;
    }
    float mx = pw;
    #pragma unroll
    for (int o = 32; o > 0; o >>= 1) mx = fmaxf(mx, __shfl_xor(mx, o));
    const unsigned long long msk = __ballot(pw == mx);
    const int argd = __ffsll(msk) - 1;     // lowest lane = first max
    if (lane == 0) toff_out[sb] = argd - 10;
}

// ---------------------------------------------------------------------------
// h_avg entry i for stream s, batch b, antenna a: mean over 4 of ls * ph_m.
// ---------------------------------------------------------------------------
__device__ __forceinline__ float2 havg_entry(
    const float* __restrict__ lsr, const float* __restrict__ lsi,
    const float2* __restrict__ phT, const float2* __restrict__ phI,
    int s, int b, int a, int tf, int i, float2 emp)
{
    const size_t base = ((size_t)(s * B + b) * A + a) * L + 4 * i;
    const float4 xr = *(const float4*)(lsr + base);
    const float4 xi = *(const float4*)(lsi + base);
    const float2 w2 = cmul(phI[s * L + 4 * i], phT[tf * L + 4 * i]);
    float wr = w2.x, wi = w2.y;
    float are, aim, nr;
    are  = xr.x * wr - xi.x * wi;  aim  = xr.x * wi + xi.x * wr;
    nr = wr * emp.x - wi * emp.y;  wi = wr * emp.y + wi * emp.x;  wr = nr;
    are += xr.y * wr - xi.y * wi;  aim += xr.y * wi + xi.y * wr;
    nr = wr * emp.x - wi * emp.y;  wi = wr * emp.y + wi * emp.x;  wr = nr;
    are += xr.z * wr - xi.z * wi;  aim += xr.z * wi + xi.z * wr;
    nr = wr * emp.x - wi * emp.y;  wi = wr * emp.y + wi * emp.x;  wr = nr;
    are += xr.w * wr - xi.w * wi;  aim += xr.w * wi + xi.w * wr;
    return make_float2(are * 0.25f, aim * 0.25f);
}

// ---------------------------------------------------------------------------
// Kernel 2: per (b,a,l). Pure streaming: per-thread h_avg recompute (i0,i1),
// interp, residual over s, apply + timing recovery. No LDS, no barriers,
// zero trig, plain stores.
// ---------------------------------------------------------------------------
__global__ __launch_bounds__(256)
void k_final(const float* __restrict__ lsr, const float* __restrict__ lsi,
             const int* __restrict__ toff_arr,
             const float2* __restrict__ phT, const float2* __restrict__ phI,
             float* __restrict__ out)
{
    const int bid = blockIdx.x;
    const int chunk = bid % NCHUNK;
    const int ba = bid / NCHUNK;
    const int b = ba >> 2;
    const int a = ba & 3;
    const int l = chunk * 256 + (int)threadIdx.x;
    if (l >= L) return;

    float t2 = ((float)l - 1.5f) * 0.25f;
    t2 = fminf(fmaxf(t2, 0.0f), (float)(R - 1));
    const int i0 = (int)t2;
    const int i1 = min(i0 + 1, R - 1);
    const float frac = t2 - (float)i0;

    float hire[S], hiim[S], pmre[S], pmim[S], ptre[S], ptim[S];
    float rre = 0.f, rim = 0.f;

    #pragma unroll
    for (int s = 0; s < S; ++s) {
        const int tf = toff_arr[s * B + b] + 10;       // row in phT
        const float2 emp = cmul(phI[s * L + 1], phT[tf * L + 1]);
        const float2 h0 = havg_entry(lsr, lsi, phT, phI, s, b, a, tf, i0, emp);
        const float2 h1 = havg_entry(lsr, lsi, phT, phI, s, b, a, tf, i1, emp);
        const float hr = h0.x * (1.f - frac) + h1.x * frac;
        const float hi = h0.y * (1.f - frac) + h1.y * frac;
        const float2 pt = phT[tf * L + l];
        const float2 wm = cmul(phI[s * L + l], pt);
        hire[s] = hr; hiim[s] = hi;
        pmre[s] = wm.x; pmim[s] = wm.y;
        ptre[s] = pt.x; ptim[s] = pt.y;
        rre += hr * wm.x + hi * wm.y;                  // h * conj(ph_m)
        rim += hi * wm.x - hr * wm.y;
    }

    const size_t off0 = ((size_t)(b * A + a)) * L + l;
    const float resre = lsr[off0] - rre;
    const float resim = lsi[off0] - rim;

    #pragma unroll
    for (int s = 0; s < S; ++s) {
        const float wre = hire[s] + resre * pmre[s] - resim * pmim[s];
        const float wim = hiim[s] + resre * pmim[s] + resim * pmre[s];
        const float fre = wre * ptre[s] + wim * ptim[s];   // * conj(ph_T)
        const float fim = wim * ptre[s] - wre * ptim[s];
        const size_t o = (((size_t)(s * B + b)) * A + a) * L + l;
        out[o] = fre;
        out[(size_t)S * B * A * L + o] = fim;
    }
}

}  // namespace

extern "C" void kernel_launch(void* const* d_in, const int* in_sizes, int n_in,
                              void* d_out, int out_size, void* d_ws, size_t ws_size,
                              hipStream_t stream) {
    (void)in_sizes; (void)n_in; (void)out_size; (void)ws_size;
    const float* lsr = (const float*)d_in[0];
    const float* lsi = (const float*)d_in[1];
    const int*   cs  = (const int*)d_in[2];
    // d_in[3] (noise_powers) unused: mmse_module is identity.

    int* toff = (int*)d_ws;                                    // 512 ints @ 0
    float2* phT  = (float2*)((char*)d_ws + 4096);              // 548352 B
    float2* phI  = (float2*)((char*)d_ws + 552448);            // 208896 B
    float2* tw   = (float2*)((char*)d_ws + 761344);            // 26112 B
    float*  powb = (float*)((char*)d_ws + 787456);             // 172032 B

    const int ntab = ((NOFF + S + 1) * L + 255) / 256;
    k_tables<<<ntab, 256, 0, stream>>>(cs, phT, phI, tw);
    k_dft   <<<S * B * A, 512, 0, stream>>>(lsr, lsi, cs, phT, phI, tw, powb);
    k_argmax<<<S * B, 64, 0, stream>>>(powb, toff);
    k_final <<<B * A * NCHUNK, 256, 0, stream>>>(lsr, lsi, toff, phT, phI,
                                                 (float*)d_out);
}